// Round 6
// baseline (670.739 us; speedup 1.0000x reference)
//
#include <hip/hip_runtime.h>
#include <math.h>

// Problem constants
// n=4096, input_dim=1024, w=64, sub_dim=256, H=8, D=64, H*D=512
#define EPSF 1e-5f

// ---------------------------------------------------------------------------
// K1: LayerNorm rows of 1024 (x -> xln)
// ---------------------------------------------------------------------------
__global__ __launch_bounds__(256) void ln1024(const float* __restrict__ in,
                                              float* __restrict__ out)
{
    int row = blockIdx.x, tid = threadIdx.x;
    const float4* ip = (const float4*)(in + (size_t)row * 1024);
    float4 v = ip[tid];
    float s  = v.x + v.y + v.z + v.w;
    float s2 = v.x*v.x + v.y*v.y + v.z*v.z + v.w*v.w;
#pragma unroll
    for (int o = 32; o; o >>= 1) { s += __shfl_down(s, o); s2 += __shfl_down(s2, o); }
    __shared__ float ps[8];
    int wv = tid >> 6;
    if ((tid & 63) == 0) { ps[wv] = s; ps[4 + wv] = s2; }
    __syncthreads();
    float st  = ps[0] + ps[1] + ps[2] + ps[3];
    float st2 = ps[4] + ps[5] + ps[6] + ps[7];
    float mu = st * (1.f / 1024.f);
    float r  = rsqrtf(st2 * (1.f / 1024.f) - mu * mu + EPSF);
    float4 o;
    o.x = (v.x - mu) * r; o.y = (v.y - mu) * r;
    o.z = (v.z - mu) * r; o.w = (v.w - mu) * r;
    ((float4*)(out + (size_t)row * 1024))[tid] = o;
}

// ---------------------------------------------------------------------------
// Generic f32 GEMM: C[m, nn] = sum_k A[m,k] * B[nn,k]  (B transposed layout)
// 64x64 tile, 256 threads, 4x4 per thread, BK=16.
// lda/ldb/ldc row strides; *_z = per-blockIdx.z element offsets (block-diag).
// M = gridDim.y*64 rows, N = gridDim.x*64 cols (exact).
// ---------------------------------------------------------------------------
__global__ __launch_bounds__(256) void gemm_bt(
    const float* __restrict__ A, int lda, int a_z,
    const float* __restrict__ B, int ldb, int b_z,
    const float* __restrict__ bias,
    float* __restrict__ C, int ldc, int c_z,
    int K)
{
    __shared__ float As[16][68];
    __shared__ float Bs[16][68];
    int z = blockIdx.z;
    A += (size_t)z * a_z; B += (size_t)z * b_z; C += (size_t)z * c_z;
    int bm = blockIdx.y, bn = blockIdx.x;
    int tid = threadIdx.x;
    int tx = tid & 15, ty = tid >> 4;
    int lrow = tid >> 2, lkq = tid & 3;
    const float* Ap = A + (size_t)(bm * 64 + lrow) * lda + lkq * 4;
    const float* Bp = B + (size_t)(bn * 64 + lrow) * ldb + lkq * 4;
    float acc[4][4] = {};
    for (int k0 = 0; k0 < K; k0 += 16) {
        float4 a = *(const float4*)(Ap + k0);
        float4 b = *(const float4*)(Bp + k0);
        __syncthreads();
        As[lkq*4+0][lrow] = a.x; As[lkq*4+1][lrow] = a.y;
        As[lkq*4+2][lrow] = a.z; As[lkq*4+3][lrow] = a.w;
        Bs[lkq*4+0][lrow] = b.x; Bs[lkq*4+1][lrow] = b.y;
        Bs[lkq*4+2][lrow] = b.z; Bs[lkq*4+3][lrow] = b.w;
        __syncthreads();
#pragma unroll
        for (int kk = 0; kk < 16; kk++) {
            float4 av = *(const float4*)&As[kk][ty * 4];
            float4 bv = *(const float4*)&Bs[kk][tx * 4];
            float am[4] = {av.x, av.y, av.z, av.w};
            float bb[4] = {bv.x, bv.y, bv.z, bv.w};
#pragma unroll
            for (int i = 0; i < 4; i++)
#pragma unroll
                for (int j = 0; j < 4; j++)
                    acc[i][j] += am[i] * bb[j];
        }
    }
#pragma unroll
    for (int i = 0; i < 4; i++) {
        int row = bm * 64 + ty * 4 + i;
#pragma unroll
        for (int j = 0; j < 4; j++) {
            int col = bn * 64 + tx * 4 + j;
            float v = acc[i][j];
            if (bias) v += bias[col];
            C[(size_t)row * ldc + col] = v;
        }
    }
}

// ---------------------------------------------------------------------------
// K3: qk_proj[n,h,c] = sum_d q[n,h,d] * Wkv[h*128+d, c]
// grid = (64 n-blocks, 8 heads), 256 threads; thread owns column c = tid.
// ---------------------------------------------------------------------------
__global__ __launch_bounds__(256) void qkproj(const float* __restrict__ qu,
                                              const float* __restrict__ Wkv,
                                              float* __restrict__ qkp)
{
    __shared__ float qs[64][65];
    int n0 = blockIdx.x * 64;
    int h  = blockIdx.y;
    int tid = threadIdx.x;
    for (int i = tid; i < 4096; i += 256) {
        int nl = i >> 6, d = i & 63;
        qs[nl][d] = qu[(size_t)(n0 + nl) * 1024 + h * 128 + d];
    }
    float wk[64];
#pragma unroll
    for (int d = 0; d < 64; d++) wk[d] = Wkv[(size_t)(h * 128 + d) * 256 + tid];
    __syncthreads();
    for (int nl = 0; nl < 64; nl += 4) {
        float a0 = 0, a1 = 0, a2 = 0, a3 = 0;
#pragma unroll
        for (int d = 0; d < 64; d++) {
            float w = wk[d];
            a0 += qs[nl + 0][d] * w; a1 += qs[nl + 1][d] * w;
            a2 += qs[nl + 2][d] * w; a3 += qs[nl + 3][d] * w;
        }
        size_t base = (size_t)(n0 + nl) * 2048 + h * 256 + tid;
        qkp[base]          = a0;
        qkp[base + 2048]   = a1;
        qkp[base + 4096]   = a2;
        qkp[base + 6144]   = a3;
    }
}

// ---------------------------------------------------------------------------
// K4: attention core. One block per n.
//   - fused LN of subseq_emb rows (w chunks of 32)
//   - scores[h,w] = silu(0.125 * dot(qkp[n,h], ls[w])) / 64
//   - ctx[h,c]   += scores[h,w] * ls[w,c]
// writes ctx (n, 8, 256)
// ---------------------------------------------------------------------------
__global__ __launch_bounds__(256) void attn_core(const float* __restrict__ sub,
                                                 const float* __restrict__ qkp,
                                                 float* __restrict__ ctx)
{
    __shared__ float ls[32][260];   // row stride 260: float4-aligned, bank spread
    __shared__ float qk[8][256];
    __shared__ float sc[8][32];
    int n = blockIdx.x;
    int tid = threadIdx.x;
    int lane = tid & 63, wv = tid >> 6;
    for (int i = tid; i < 2048; i += 256) qk[i >> 8][i & 255] = qkp[(size_t)n * 2048 + i];
    float ctxr[8] = {0, 0, 0, 0, 0, 0, 0, 0};
    const float* subn = sub + (size_t)n * (64 * 256);
    for (int w0 = 0; w0 < 64; w0 += 32) {
        __syncthreads();   // protects ls/sc from prev-iter readers; orders qk load
        // LayerNorm 32 rows of 256; each wave does 8 rows
#pragma unroll
        for (int i = 0; i < 8; i++) {
            int wl = wv * 8 + i;
            const float* rp = subn + (size_t)(w0 + wl) * 256;
            float v0 = rp[lane], v1 = rp[lane + 64], v2 = rp[lane + 128], v3 = rp[lane + 192];
            float s  = v0 + v1 + v2 + v3;
            float s2 = v0*v0 + v1*v1 + v2*v2 + v3*v3;
#pragma unroll
            for (int o = 32; o; o >>= 1) { s += __shfl_down(s, o); s2 += __shfl_down(s2, o); }
            s = __shfl(s, 0); s2 = __shfl(s2, 0);
            float mu = s * (1.f / 256.f);
            float rr = rsqrtf(s2 * (1.f / 256.f) - mu * mu + EPSF);
            ls[wl][lane]       = (v0 - mu) * rr;
            ls[wl][lane + 64]  = (v1 - mu) * rr;
            ls[wl][lane + 128] = (v2 - mu) * rr;
            ls[wl][lane + 192] = (v3 - mu) * rr;
        }
        __syncthreads();
        // scores: thread = (h, w) pair
        {
            int h = tid >> 5, wl = tid & 31;
            float a = 0;
            const float4* lp = (const float4*)&ls[wl][0];
            const float4* qp = (const float4*)&qk[h][0];
#pragma unroll 8
            for (int c4 = 0; c4 < 64; c4++) {
                float4 l4 = lp[c4], q4 = qp[c4];
                a += l4.x*q4.x + l4.y*q4.y + l4.z*q4.z + l4.w*q4.w;
            }
            a *= 0.125f;
            float sig = 1.f / (1.f + __expf(-a));
            sc[h][wl] = a * sig * (1.f / 64.f);
        }
        __syncthreads();
        // ctx accumulate: thread owns column c = tid
#pragma unroll 4
        for (int wl = 0; wl < 32; wl++) {
            float l = ls[wl][tid];
#pragma unroll
            for (int hh = 0; hh < 8; hh++) ctxr[hh] += sc[hh][wl] * l;
        }
    }
    size_t base = (size_t)n * 2048 + tid;
#pragma unroll
    for (int hh = 0; hh < 8; hh++) ctx[base + hh * 256] = ctxr[hh];
}

// ---------------------------------------------------------------------------
// K6: aln_u[n,j] = layernorm(attnout[n,:512])[j] * u[n,j]
//     u[n, h*64+d] = qu[n, h*128 + 64 + d]
// ---------------------------------------------------------------------------
__global__ __launch_bounds__(256) void ln_mul_u(const float* __restrict__ attn,
                                                const float* __restrict__ qu,
                                                float* __restrict__ out)
{
    int n = blockIdx.x, tid = threadIdx.x;
    float2 v = *(const float2*)(attn + (size_t)n * 512 + tid * 2);
    float s  = v.x + v.y;
    float s2 = v.x*v.x + v.y*v.y;
#pragma unroll
    for (int o = 32; o; o >>= 1) { s += __shfl_down(s, o); s2 += __shfl_down(s2, o); }
    __shared__ float ps[8];
    int wv = tid >> 6;
    if ((tid & 63) == 0) { ps[wv] = s; ps[4 + wv] = s2; }
    __syncthreads();
    float st  = ps[0] + ps[1] + ps[2] + ps[3];
    float st2 = ps[4] + ps[5] + ps[6] + ps[7];
    float mu = st * (1.f / 512.f);
    float r  = rsqrtf(st2 * (1.f / 512.f) - mu * mu + EPSF);
    int j0 = tid * 2;
    int h = j0 >> 6, d = j0 & 63;
    const float* ub = qu + (size_t)n * 1024 + h * 128 + 64 + d;
    float2 o;
    o.x = (v.x - mu) * r * ub[0];
    o.y = (v.y - mu) * r * ub[1];
    *(float2*)(out + (size_t)n * 512 + j0) = o;
}

// ---------------------------------------------------------------------------
extern "C" void kernel_launch(void* const* d_in, const int* in_sizes, int n_in,
                              void* d_out, int out_size, void* d_ws, size_t ws_size,
                              hipStream_t stream)
{
    const float* x   = (const float*)d_in[0];
    const float* sub = (const float*)d_in[1];
    const float* Wq  = (const float*)d_in[2];
    const float* Wkv = (const float*)d_in[3];
    const float* Wo  = (const float*)d_in[4];
    const float* bo  = (const float*)d_in[5];
    float* out = (float*)d_out;

    char* ws = (char*)d_ws;
    // workspace layout (96 MB total):
    //   [0,16M)   xln   (dead after qu GEMM) -> reused: attnout @0 (8M), aln_u @8M (8M)
    //   [16,32M)  qu    (q + u, live until ln_mul_u)
    //   [32,64M)  qkp   (dead after attn_core)
    //   [64,96M)  ctx
    float* xln     = (float*)(ws);
    float* attnout = (float*)(ws);
    float* aln_u   = (float*)(ws + ((size_t)8  << 20));
    float* qu      = (float*)(ws + ((size_t)16 << 20));
    float* qkp     = (float*)(ws + ((size_t)32 << 20));
    float* ctxb    = (float*)(ws + ((size_t)64 << 20));

    // 1) xln = LN(x)                         (4096 x 1024)
    ln1024<<<4096, 256, 0, stream>>>(x, xln);
    // 2) qu = xln @ Wq.T                     (4096 x 1024) @ (1024 x 1024)^T
    gemm_bt<<<dim3(16, 64, 1), 256, 0, stream>>>(xln, 1024, 0, Wq, 1024, 0,
                                                 nullptr, qu, 1024, 0, 1024);
    // 3) qk_proj[n,h,:] = q[n,h,:] @ Wk_h    (block-diagonal)
    qkproj<<<dim3(64, 8), 256, 0, stream>>>(qu, Wkv, qkp);
    // 4) fused LN(subseq) + scores + ctx
    attn_core<<<4096, 256, 0, stream>>>(sub, qkp, ctxb);
    // 5) attnout[n, h*64+d] = ctx[n,h,:] @ Wv_h.T  (block-diagonal GEMM, z = h)
    gemm_bt<<<dim3(1, 64, 8), 256, 0, stream>>>(ctxb, 2048, 256,
                                                Wkv + 64 * 256, 256, 128 * 256,
                                                nullptr, attnout, 512, 64, 256);
    // 6) aln_u = LN(attnout) * u
    ln_mul_u<<<4096, 256, 0, stream>>>(attnout, qu, aln_u);
    // 7) out = aln_u @ Wo.T + bo             (4096 x 512) @ (1024 x 512)^T
    gemm_bt<<<dim3(16, 64, 1), 256, 0, stream>>>(aln_u, 512, 0, Wo, 512, 0,
                                                 bo, out, 1024, 0, 512);
}

// Round 7
// 524.402 us; speedup vs baseline: 1.2791x; 1.2791x over previous
//
#include <hip/hip_runtime.h>
#include <math.h>

// n=4096, input_dim=1024, w=64, sub_dim=256, H=8, D=64, H*D=512
#define EPSF 1e-5f

typedef short bf16x8 __attribute__((ext_vector_type(8)));
typedef float f32x4 __attribute__((ext_vector_type(4)));

// f32 -> bf16 bits, round-to-nearest-even (finite values)
static __device__ __forceinline__ unsigned short f2bf(float x)
{
    union { float f; unsigned int u; } v; v.f = x;
    unsigned int r = (v.u + 0x7FFFu + ((v.u >> 16) & 1u)) >> 16;
    return (unsigned short)r;
}

// ---------------------------------------------------------------------------
// K1: LayerNorm rows of 1024 (x -> xln), f32 out
// ---------------------------------------------------------------------------
__global__ __launch_bounds__(256) void ln1024(const float* __restrict__ in,
                                              float* __restrict__ out)
{
    int row = blockIdx.x, tid = threadIdx.x;
    const float4* ip = (const float4*)(in + (size_t)row * 1024);
    float4 v = ip[tid];
    float s  = v.x + v.y + v.z + v.w;
    float s2 = v.x*v.x + v.y*v.y + v.z*v.z + v.w*v.w;
#pragma unroll
    for (int o = 32; o; o >>= 1) { s += __shfl_down(s, o); s2 += __shfl_down(s2, o); }
    __shared__ float ps[8];
    int wv = tid >> 6;
    if ((tid & 63) == 0) { ps[wv] = s; ps[4 + wv] = s2; }
    __syncthreads();
    float st  = ps[0] + ps[1] + ps[2] + ps[3];
    float st2 = ps[4] + ps[5] + ps[6] + ps[7];
    float mu = st * (1.f / 1024.f);
    float r  = rsqrtf(st2 * (1.f / 1024.f) - mu * mu + EPSF);
    float4 o;
    o.x = (v.x - mu) * r; o.y = (v.y - mu) * r;
    o.z = (v.z - mu) * r; o.w = (v.w - mu) * r;
    ((float4*)(out + (size_t)row * 1024))[tid] = o;
}

// ---------------------------------------------------------------------------
// Weight prep kernels (run every call; cheap)
// Wfused_bf16 [2560][1024]: rows 0..511  = Wu  (Wq rows h*128+64+d -> row h*64+d)
//                           rows 512..2559 = W2 (combined q-proj x k-proj)
// ---------------------------------------------------------------------------
__global__ __launch_bounds__(256) void prep_wu(const float* __restrict__ Wq,
                                               unsigned short* __restrict__ Wf)
{
    int j = blockIdx.x;              // 0..511
    int h = j >> 6, d = j & 63;
    const float4* src = (const float4*)(Wq + (size_t)(h * 128 + 64 + d) * 1024);
    float4 v = src[threadIdx.x];
    ushort4 u;
    u.x = f2bf(v.x); u.y = f2bf(v.y); u.z = f2bf(v.z); u.w = f2bf(v.w);
    *(ushort4*)(Wf + (size_t)j * 1024 + threadIdx.x * 4) = u;
}

// W2[h*256+c][k] = sum_d Wq[h*128+d][k] * Wkv[h*128+d][c]   (f32 accum -> bf16)
__global__ __launch_bounds__(256) void prep_w2(const float* __restrict__ Wq,
                                               const float* __restrict__ Wkv,
                                               unsigned short* __restrict__ Wf)
{
    int nrow = blockIdx.x;           // 0..2047
    int h = nrow >> 8, c = nrow & 255;
    int tid = threadIdx.x;
    float4 acc = {0.f, 0.f, 0.f, 0.f};
    for (int d = 0; d < 64; d++) {
        float s = Wkv[(size_t)(h * 128 + d) * 256 + c];           // block-uniform
        float4 w = *(const float4*)(Wq + (size_t)(h * 128 + d) * 1024 + tid * 4);
        acc.x += w.x * s; acc.y += w.y * s; acc.z += w.z * s; acc.w += w.w * s;
    }
    ushort4 u;
    u.x = f2bf(acc.x); u.y = f2bf(acc.y); u.z = f2bf(acc.z); u.w = f2bf(acc.w);
    *(ushort4*)(Wf + (size_t)(512 + nrow) * 1024 + tid * 4) = u;
}

// Wv_bf16 [512][256]: [h*64+d][c] = Wkv[h*128+64+d][c]
__global__ __launch_bounds__(256) void prep_wv(const float* __restrict__ Wkv,
                                               unsigned short* __restrict__ Wv)
{
    int j = blockIdx.x;              // 0..511
    int h = j >> 6, d = j & 63;
    float v = Wkv[(size_t)(h * 128 + 64 + d) * 256 + threadIdx.x];
    Wv[(size_t)j * 256 + threadIdx.x] = f2bf(v);
}

// Wo_bf16 [1024][512] direct cast
__global__ __launch_bounds__(256) void prep_wo(const float* __restrict__ Wo,
                                               unsigned short* __restrict__ Wob)
{
    int j = blockIdx.x;              // 0..1023
    const float2* src = (const float2*)(Wo + (size_t)j * 512);
    float2 v = src[threadIdx.x];
    ushort2 u; u.x = f2bf(v.x); u.y = f2bf(v.y);
    *(ushort2*)(Wob + (size_t)j * 512 + threadIdx.x * 2) = u;
}

// ---------------------------------------------------------------------------
// MFMA GEMM: C[m,n] = sum_k A[m,k] * B[n,k]   (B in [N][K] "bt" layout, bf16)
// A either f32 (cast during stage) or bf16. 256 threads = 4 waves.
// Tile: BM = NWY*FM*16, BN = NWX*FN*16, BK = 32. mfma_f32_16x16x32_bf16.
// Fragment layout (guide-verified): A/B lane: row/col = l&15, k = (l>>4)*8 +0..7
//                                   C/D: col = l&15, row = (l>>4)*4 + reg
// ---------------------------------------------------------------------------
template<int FM, int FN, int NWX, int NWY, bool A_F32>
__global__ __launch_bounds__(256) void gemm_mfma(
    const void* __restrict__ Av, int lda, long long a_z,
    const unsigned short* __restrict__ B, int ldb, long long b_z,
    const float* __restrict__ bias,
    float* __restrict__ C, int ldc, long long c_z,
    int K)
{
    constexpr int BM = NWY * FM * 16;
    constexpr int BN = NWX * FN * 16;
    constexpr int LDK = 40;                        // 32 + 8 pad (80B rows: bank spread)
    __shared__ unsigned short As[BM * LDK];
    __shared__ unsigned short Bs[BN * LDK];

    const int tid = threadIdx.x, lane = tid & 63, wid = tid >> 6;
    const int wy = wid / NWX, wx = wid % NWX;
    const int z = blockIdx.z;
    const unsigned short* Bz = B + (size_t)z * b_z;
    float* Cz = C + (size_t)z * c_z;
    const int bm = blockIdx.y * BM, bn = blockIdx.x * BN;

    f32x4 acc[FM][FN] = {};
    const int fr_row = lane & 15;
    const int fr_k   = (lane >> 4) * 8;

    for (int k0 = 0; k0 < K; k0 += 32) {
        __syncthreads();
        if constexpr (A_F32) {
            const float* A = (const float*)Av + (size_t)z * a_z;
            int r = tid >> 3, kq = tid & 7;        // 8 thr/row, 32 rows/pass
#pragma unroll
            for (int p = 0; p < BM / 32; p++) {
                float4 v = *(const float4*)(A + (size_t)(bm + r + p * 32) * lda + k0 + kq * 4);
                ushort4 u;
                u.x = f2bf(v.x); u.y = f2bf(v.y); u.z = f2bf(v.z); u.w = f2bf(v.w);
                *(ushort4*)(&As[(r + p * 32) * LDK + kq * 4]) = u;
            }
        } else {
            const unsigned short* A = (const unsigned short*)Av + (size_t)z * a_z;
            int r = tid >> 2, kq = tid & 3;        // 4 thr/row, 64 rows/pass
#pragma unroll
            for (int p = 0; p < BM / 64; p++) {
                int4 v = *(const int4*)(A + (size_t)(bm + r + p * 64) * lda + k0 + kq * 8);
                *(int4*)(&As[(r + p * 64) * LDK + kq * 8]) = v;
            }
        }
        {
            int r = tid >> 2, kq = tid & 3;
#pragma unroll
            for (int p = 0; p < BN / 64; p++) {
                int4 v = *(const int4*)(Bz + (size_t)(bn + r + p * 64) * ldb + k0 + kq * 8);
                *(int4*)(&Bs[(r + p * 64) * LDK + kq * 8]) = v;
            }
        }
        __syncthreads();
        bf16x8 af[FM], bf[FN];
#pragma unroll
        for (int i = 0; i < FM; i++)
            af[i] = *(const bf16x8*)(&As[(wy * FM * 16 + i * 16 + fr_row) * LDK + fr_k]);
#pragma unroll
        for (int j = 0; j < FN; j++)
            bf[j] = *(const bf16x8*)(&Bs[(wx * FN * 16 + j * 16 + fr_row) * LDK + fr_k]);
#pragma unroll
        for (int i = 0; i < FM; i++)
#pragma unroll
            for (int j = 0; j < FN; j++)
                acc[i][j] = __builtin_amdgcn_mfma_f32_16x16x32_bf16(af[i], bf[j], acc[i][j], 0, 0, 0);
    }

    const int ccol = lane & 15, crow4 = (lane >> 4) * 4;
#pragma unroll
    for (int i = 0; i < FM; i++)
#pragma unroll
        for (int j = 0; j < FN; j++) {
            int col = bn + wx * FN * 16 + j * 16 + ccol;
            float bv = bias ? bias[col] : 0.f;
#pragma unroll
            for (int r = 0; r < 4; r++) {
                int row = bm + wy * FM * 16 + i * 16 + crow4 + r;
                Cz[(size_t)row * ldc + col] = acc[i][j][r] + bv;
            }
        }
}

// ---------------------------------------------------------------------------
// attn core. One block per n. Reads qk_proj from fused F (stride 2560, off 512),
// fused LN of subseq rows, silu scores, accumulates ctx -> bf16 out.
// ---------------------------------------------------------------------------
__global__ __launch_bounds__(256) void attn_core(const float* __restrict__ sub,
                                                 const float* __restrict__ F,
                                                 unsigned short* __restrict__ ctx)
{
    __shared__ float ls[32][260];
    __shared__ float qk[8][256];
    __shared__ float sc[8][32];
    int n = blockIdx.x;
    int tid = threadIdx.x;
    int lane = tid & 63, wv = tid >> 6;
    for (int i = tid; i < 2048; i += 256)
        qk[i >> 8][i & 255] = F[(size_t)n * 2560 + 512 + i];
    float ctxr[8] = {0, 0, 0, 0, 0, 0, 0, 0};
    const float* subn = sub + (size_t)n * (64 * 256);
    for (int w0 = 0; w0 < 64; w0 += 32) {
        __syncthreads();
#pragma unroll
        for (int i = 0; i < 8; i++) {
            int wl = wv * 8 + i;
            const float* rp = subn + (size_t)(w0 + wl) * 256;
            float v0 = rp[lane], v1 = rp[lane + 64], v2 = rp[lane + 128], v3 = rp[lane + 192];
            float s  = v0 + v1 + v2 + v3;
            float s2 = v0*v0 + v1*v1 + v2*v2 + v3*v3;
#pragma unroll
            for (int o = 32; o; o >>= 1) { s += __shfl_down(s, o); s2 += __shfl_down(s2, o); }
            s = __shfl(s, 0); s2 = __shfl(s2, 0);
            float mu = s * (1.f / 256.f);
            float rr = rsqrtf(s2 * (1.f / 256.f) - mu * mu + EPSF);
            ls[wl][lane]       = (v0 - mu) * rr;
            ls[wl][lane + 64]  = (v1 - mu) * rr;
            ls[wl][lane + 128] = (v2 - mu) * rr;
            ls[wl][lane + 192] = (v3 - mu) * rr;
        }
        __syncthreads();
        {
            int h = tid >> 5, wl = tid & 31;
            float a = 0;
            const float4* lp = (const float4*)&ls[wl][0];
            const float4* qp = (const float4*)&qk[h][0];
#pragma unroll 8
            for (int c4 = 0; c4 < 64; c4++) {
                float4 l4 = lp[c4], q4 = qp[c4];
                a += l4.x*q4.x + l4.y*q4.y + l4.z*q4.z + l4.w*q4.w;
            }
            a *= 0.125f;
            float sig = 1.f / (1.f + __expf(-a));
            sc[h][wl] = a * sig * (1.f / 64.f);
        }
        __syncthreads();
#pragma unroll 4
        for (int wl = 0; wl < 32; wl++) {
            float l = ls[wl][tid];
#pragma unroll
            for (int hh = 0; hh < 8; hh++) ctxr[hh] += sc[hh][wl] * l;
        }
    }
    size_t base = (size_t)n * 2048 + tid;
#pragma unroll
    for (int hh = 0; hh < 8; hh++) ctx[base + hh * 256] = f2bf(ctxr[hh]);
}

// ---------------------------------------------------------------------------
// ln_mul_u: aln_u[n,j] = LN(attnout[n,:512])[j] * u[n,j]  -> bf16
// u[n,j] = F[n*2560 + j]  (Wu pre-permuted: j = h*64+d)
// ---------------------------------------------------------------------------
__global__ __launch_bounds__(256) void ln_mul_u(const float* __restrict__ attn,
                                                const float* __restrict__ F,
                                                unsigned short* __restrict__ out)
{
    int n = blockIdx.x, tid = threadIdx.x;
    float2 v = *(const float2*)(attn + (size_t)n * 512 + tid * 2);
    float s  = v.x + v.y;
    float s2 = v.x*v.x + v.y*v.y;
#pragma unroll
    for (int o = 32; o; o >>= 1) { s += __shfl_down(s, o); s2 += __shfl_down(s2, o); }
    __shared__ float ps[8];
    int wv = tid >> 6;
    if ((tid & 63) == 0) { ps[wv] = s; ps[4 + wv] = s2; }
    __syncthreads();
    float st  = ps[0] + ps[1] + ps[2] + ps[3];
    float st2 = ps[4] + ps[5] + ps[6] + ps[7];
    float mu = st * (1.f / 512.f);
    float r  = rsqrtf(st2 * (1.f / 512.f) - mu * mu + EPSF);
    int j0 = tid * 2;
    const float* ub = F + (size_t)n * 2560 + j0;
    ushort2 o;
    o.x = f2bf((v.x - mu) * r * ub[0]);
    o.y = f2bf((v.y - mu) * r * ub[1]);
    *(ushort2*)(out + (size_t)n * 512 + j0) = o;
}

// ---------------------------------------------------------------------------
extern "C" void kernel_launch(void* const* d_in, const int* in_sizes, int n_in,
                              void* d_out, int out_size, void* d_ws, size_t ws_size,
                              hipStream_t stream)
{
    const float* x   = (const float*)d_in[0];
    const float* sub = (const float*)d_in[1];
    const float* Wq  = (const float*)d_in[2];
    const float* Wkv = (const float*)d_in[3];
    const float* Wo  = (const float*)d_in[4];
    const float* bo  = (const float*)d_in[5];
    float* out = (float*)d_out;

    char* ws = (char*)d_ws;
    // workspace map (91 MB):
    float*          xln   = (float*)(ws);                          // [0,16M)
    float*          F     = (float*)(ws + ((size_t)16 << 20));     // [16,56M) 4096x2560
    unsigned short* ctxb  = (unsigned short*)(ws + ((size_t)56 << 20)); // [56,72M)
    float*          attno = (float*)(ws + ((size_t)72 << 20));     // [72,80M)
    unsigned short* alnu  = (unsigned short*)(ws + ((size_t)80 << 20)); // [80,84M)
    unsigned short* Wf    = (unsigned short*)(ws + ((size_t)84 << 20)); // [84,89M)
    unsigned short* Wv    = (unsigned short*)(ws + ((size_t)89 << 20)); // [89,89.25M)
    unsigned short* Wob   = (unsigned short*)(ws + ((size_t)90 << 20)); // [90,91M)

    // weight prep (bf16)
    prep_wu<<<512,  256, 0, stream>>>(Wq, Wf);
    prep_w2<<<2048, 256, 0, stream>>>(Wq, Wkv, Wf);
    prep_wv<<<512,  256, 0, stream>>>(Wkv, Wv);
    prep_wo<<<1024, 256, 0, stream>>>(Wo, Wob);

    // 1) xln = LN(x)
    ln1024<<<4096, 256, 0, stream>>>(x, xln);

    // 2) F = xln @ Wfused.T : [u (512) | qk_proj (2048)]  M=4096 N=2560 K=1024
    gemm_mfma<4, 4, 2, 2, true><<<dim3(20, 32, 1), 256, 0, stream>>>(
        xln, 1024, 0, Wf, 1024, 0, nullptr, F, 2560, 0, 1024);

    // 3) fused LN(subseq) + scores + ctx (bf16)
    attn_core<<<4096, 256, 0, stream>>>(sub, F, ctxb);

    // 4) attnout[n, h*64+d] = ctx_h @ Wv_h.T  (block-diag, z=h) M=4096 N=64 K=256
    gemm_mfma<2, 4, 1, 4, false><<<dim3(1, 32, 8), 256, 0, stream>>>(
        ctxb, 2048, 256, Wv, 256, 64 * 256, nullptr, attno, 512, 64, 256);

    // 5) aln_u = LN(attnout) * u  -> bf16
    ln_mul_u<<<4096, 256, 0, stream>>>(attno, F, alnu);

    // 6) out = aln_u @ Wo.T + bo  M=4096 N=1024 K=512
    gemm_mfma<4, 4, 2, 2, false><<<dim3(8, 32, 1), 256, 0, stream>>>(
        alnu, 512, 0, Wob, 512, 0, bo, out, 1024, 0, 512);
}